// Round 8
// baseline (35.990 us; speedup 1.0000x reference)
//
#include <hip/hip_runtime.h>
#include <hip/hip_fp16.h>
#include <math.h>

#define NMODES 4096
#define NGRID  8192
#define BATCH  16
#define NPTS   131072
#define GSCALE 1048576.0f            // 2^20  (exact)
#define WSCALE 9.5367431640625e-07f  // 2^-20 (exact)

// ---------------------------------------------------------------------------
// Deconvolution factor: (-1)^fidx / phi_hat(fidx), I0 asymptotic (z~18).
// ---------------------------------------------------------------------------
__device__ __forceinline__ float deconv_signed(int fidx) {
    float k = (float)(fidx - 2048);
    float t = k * 7.66990393942820614e-4f;                 // 2*pi*k/n
    float z = 4.0f * sqrtf(22.2066099024510563f - t * t);  // m*sqrt(b^2-t^2)
    float iz = 1.0f / z;
    float p  = 1.0f + iz * (0.125f + iz * (0.0703125f +
               iz * (0.0732421875f + iz * 0.112152099609375f)));
    float phi = __expf(z) * p * rsqrtf(6.28318530717958648f * z);
    float s = (fidx & 1) ? -1.0f : 1.0f;
    return s / phi;
}

// ---------------------------------------------------------------------------
// Kernel A (unchanged from R7): one block per batch; bit-rev scatter build,
// 13 in-place DIT stages, store g[t] = (-1)^t H[t] natural-order.
// ---------------------------------------------------------------------------
__global__ __launch_bounds__(1024) void nfft_fft_kernel(
    const float* __restrict__ fr, const float* __restrict__ fi,
    float2* __restrict__ g)
{
    __shared__ float2 buf[NGRID];    // 64 KB
    const int b   = blockIdx.x;
    const int tid = threadIdx.x;

    for (int j = tid; j < NGRID; j += 1024) {
        float2 v = make_float2(0.0f, 0.0f);
        if (j >= 2048 && j < 6144) {
            int fidx = j - 2048;
            float inv = deconv_signed(fidx);
            v.x = fr[b * NMODES + fidx] * inv;
            v.y = fi[b * NMODES + fidx] * inv;
        }
        int rb = (int)(__brev((unsigned)j) >> 19);
        buf[rb] = v;
    }
    __syncthreads();

    for (int s = 0; s <= 12; ++s) {
        const int   half = 1 << s;
        const float tscl = -0.5f / (float)half;   // turns per pos
#pragma unroll
        for (int ii = 0; ii < 4; ++ii) {
            int i = tid + ii * 1024;
            int pos = i & (half - 1);
            int idx = ((i ^ pos) << 1) | pos;
            float sn = __builtin_amdgcn_sinf(tscl * (float)pos);
            float cs = __builtin_amdgcn_cosf(tscl * (float)pos);
            float2 a = buf[idx];
            float2 t = buf[idx + half];
            float2 bt = make_float2(t.x * cs - t.y * sn,
                                    t.x * sn + t.y * cs);
            buf[idx]        = make_float2(a.x + bt.x, a.y + bt.y);
            buf[idx + half] = make_float2(a.x - bt.x, a.y - bt.y);
        }
        __syncthreads();
    }

    for (int t = tid; t < NGRID; t += 1024) {
        float2 v = buf[t];
        if (t & 1) { v.x = -v.x; v.y = -v.y; }
        g[b * NGRID + t] = v;
    }
}

// ---------------------------------------------------------------------------
// Kernel B: fp16-staged g (scaled 2^20, 32 KB) + window lerp table over frac
// (w[8][513], scaled 2^-20, 16.4 KB; stride 513 -> bank (l+i)%32, conflict-
// free). Per tap: 2 LDS b32 + lerp fma + half2 gather. 4 pts/thread, float4 IO.
// ---------------------------------------------------------------------------
__global__ __launch_bounds__(1024) void nfft_interp_kernel(
    const float* __restrict__ x, const float2* __restrict__ g,
    float* __restrict__ out, int cplx)
{
    __shared__ __half2 gl16[NGRID];      // 32 KB
    __shared__ float   wtab[8 * 513];    // 16.4 KB

    const int b   = blockIdx.x >> 5;
    const int blk = blockIdx.x & 31;
    const int tid = threadIdx.x;

    // stage g -> scaled fp16 pairs
    const float4* gs = (const float4*)(g + b * NGRID);
    for (int i = tid; i < NGRID / 2; i += 1024) {
        float4 v = gs[i];
        gl16[2 * i]     = __floats2half2_rn(v.x * GSCALE, v.y * GSCALE);
        gl16[2 * i + 1] = __floats2half2_rn(v.z * GSCALE, v.w * GSCALE);
    }
    // build window lerp table: node i -> frac = i/512, tap l -> u = (4-l)-frac
    for (int t = tid; t < 8 * 513; t += 1024) {
        int   l    = t / 513;
        int   i    = t - l * 513;
        float frac = (float)i * (1.0f / 512.0f);
        float u    = (float)(4 - l) - frac;
        float arg2 = 16.0f - u * u;
        float w    = 0.0f;
        if (arg2 > 0.0f) {
            float r   = rsqrtf(arg2);
            float arg = arg2 * r;
            float z   = 4.71238898038468986f * arg;
            w = (__expf(z) - __expf(-z)) * 0.15915494309189533577f * r;
        }
        wtab[t] = w * WSCALE;
    }
    __syncthreads();

    const int base = b * NPTS + blk * 4096;
    const float4 xv4 = ((const float4*)(x + base))[tid];   // 4 consecutive pts
    float outre[4], outim[4];

#pragma unroll
    for (int q = 0; q < 4; ++q) {
        float xv = (q == 0) ? xv4.x : (q == 1) ? xv4.y : (q == 2) ? xv4.z : xv4.w;
        float fl   = xv * 8192.0f;                 // exact (2^13 scale)
        float cf   = ceilf(fl);
        int   c    = (int)cf;
        float frac = cf - fl;                      // [0,1)
        float tt   = frac * 512.0f;
        int   ti   = (int)tt;                      // 0..511
        float fr2  = tt - (float)ti;
        int   wr0  = (c + 12284) & (NGRID - 1);    // (c-4+n/2) mod n
        float re = 0.0f, im = 0.0f;
#pragma unroll
        for (int l = 0; l < 8; ++l) {
            float w0 = wtab[l * 513 + ti];
            float w1 = wtab[l * 513 + ti + 1];
            float w  = fmaf(fr2, w1 - w0, w0);
            float2 gv = __half22float2(gl16[(wr0 + l) & (NGRID - 1)]);
            re = fmaf(w, gv.x, re);
            im = fmaf(w, gv.y, im);
        }
        outre[q] = re; outim[q] = im;
    }

    if (cplx) {
        float2* o = ((float2*)out) + base + tid * 4;
        o[0] = make_float2(outre[0], outim[0]);
        o[1] = make_float2(outre[1], outim[1]);
        o[2] = make_float2(outre[2], outim[2]);
        o[3] = make_float2(outre[3], outim[3]);
    } else {
        ((float4*)(out + base))[tid] =
            make_float4(outre[0], outre[1], outre[2], outre[3]);
    }
}

// ---------------------------------------------------------------------------
// Fallback: fully fused single kernel (proven in R4/R7) if d_ws too small.
// ---------------------------------------------------------------------------
__global__ __launch_bounds__(1024) void nfft_fused_kernel(
    const float* __restrict__ x, const float* __restrict__ fr,
    const float* __restrict__ fi, float* __restrict__ out, int cplx)
{
    __shared__ float2 buf[NGRID];
    const int b   = blockIdx.x >> 5;
    const int blk = blockIdx.x & 31;
    const int tid = threadIdx.x;

    for (int j = tid; j < NGRID; j += 1024) {
        float2 v = make_float2(0.0f, 0.0f);
        if (j >= 2048 && j < 6144) {
            int fidx = j - 2048;
            float inv = deconv_signed(fidx);
            v.x = fr[b * NMODES + fidx] * inv;
            v.y = fi[b * NMODES + fidx] * inv;
        }
        buf[j] = v;
    }
    __syncthreads();

    for (int s = 12; s >= 0; --s) {
        const int   half = 1 << s;
        const float tscl = -0.5f / (float)half;
#pragma unroll
        for (int ii = 0; ii < 4; ++ii) {
            int i = tid + ii * 1024;
            int pos = i & (half - 1);
            int idx = ((i ^ pos) << 1) | pos;
            float sn = __builtin_amdgcn_sinf(tscl * (float)pos);
            float cs = __builtin_amdgcn_cosf(tscl * (float)pos);
            float2 a = buf[idx];
            float2 c = buf[idx + half];
            buf[idx] = make_float2(a.x + c.x, a.y + c.y);
            float2 d = make_float2(a.x - c.x, a.y - c.y);
            buf[idx + half] = make_float2(d.x * cs - d.y * sn,
                                          d.x * sn + d.y * cs);
        }
        __syncthreads();
    }

    const int base = b * NPTS + blk * 4096;
    for (int p = tid; p < 4096; p += 1024) {
        float xv   = x[base + p];
        float fl   = xv * 8192.0f;
        int   c    = (int)ceilf(fl);
        float frac = (float)c - fl;
        float re = 0.0f, im = 0.0f;
#pragma unroll
        for (int l = 0; l < 8; ++l) {
            int   ind  = c - 4 + l;
            float u    = (float)(4 - l) - frac;
            float arg2 = 16.0f - u * u;
            float w    = 0.0f;
            if (arg2 > 0.0f) {
                float r   = rsqrtf(arg2);
                float arg = arg2 * r;
                float z   = 4.71238898038468986f * arg;
                w = (__expf(z) - __expf(-z)) * 0.15915494309189533577f * r;
            }
            if (ind & 1) w = -w;
            int wr = (ind + 4096) & (NGRID - 1);
            int rb = (int)(__brev((unsigned)wr) >> 19);
            float2 gv = buf[rb];
            re = fmaf(w, gv.x, re);
            im = fmaf(w, gv.y, im);
        }
        if (cplx) ((float2*)out)[base + p] = make_float2(re, im);
        else      out[base + p] = re;
    }
}

extern "C" void kernel_launch(void* const* d_in, const int* in_sizes, int n_in,
                              void* d_out, int out_size, void* d_ws, size_t ws_size,
                              hipStream_t stream) {
    (void)in_sizes; (void)n_in;
    const float* x  = (const float*)d_in[0];
    const float* fr = (const float*)d_in[1];
    const float* fi = (const float*)d_in[2];

    const int cplx = (out_size >= BATCH * NPTS * 2) ? 1 : 0;
    const size_t g_bytes = (size_t)BATCH * NGRID * sizeof(float2);  // 1 MB

    if (ws_size >= g_bytes) {
        float2* g = (float2*)d_ws;
        nfft_fft_kernel<<<BATCH, 1024, 0, stream>>>(fr, fi, g);
        nfft_interp_kernel<<<BATCH * 32, 1024, 0, stream>>>(
            x, g, (float*)d_out, cplx);
    } else {
        nfft_fused_kernel<<<BATCH * 32, 1024, 0, stream>>>(
            x, fr, fi, (float*)d_out, cplx);
    }
}

// Round 9
// 29.469 us; speedup vs baseline: 1.2213x; 1.2213x over previous
//
#include <hip/hip_runtime.h>
#include <math.h>

#define NMODES 4096
#define NGRID  8192
#define BATCH  16
#define NPTS   131072

__device__ __forceinline__ float2 cmul(float2 a, float2 b) {
    return make_float2(a.x * b.x - a.y * b.y, a.x * b.y + a.y * b.x);
}

// ---------------------------------------------------------------------------
// Deconvolution factor: (-1)^fidx / phi_hat(fidx), I0 asymptotic (z~18).
// ---------------------------------------------------------------------------
__device__ __forceinline__ float deconv_signed(int fidx) {
    float k = (float)(fidx - 2048);
    float t = k * 7.66990393942820614e-4f;                 // 2*pi*k/n
    float z = 4.0f * sqrtf(22.2066099024510563f - t * t);  // m*sqrt(b^2-t^2)
    float iz = 1.0f / z;
    float p  = 1.0f + iz * (0.125f + iz * (0.0703125f +
               iz * (0.0732421875f + iz * 0.112152099609375f)));
    float phi = __expf(z) * p * rsqrtf(6.28318530717958648f * z);
    float s = (fidx & 1) ? -1.0f : 1.0f;
    return s / phi;
}

// ---------------------------------------------------------------------------
// Four-step FFT, step 1+2.  n = n2 + 512*n1 (n1=0..15); pad => n1 in [4,12).
// C[k1][n2] = sum_{r=0..7} h[n2+512*(r+4)] * W16^{(r+4)*k1},  then
// *= W8192^{n2*k1}.  Output gg[b][k1 + 16*n2].
// Grid: BATCH*8 blocks (64 n2 per block), 1024 threads = (k1=tid>>6, n2l=tid&63).
// ---------------------------------------------------------------------------
__global__ __launch_bounds__(1024) void nfft_f1_kernel(
    const float* __restrict__ fr, const float* __restrict__ fi,
    float2* __restrict__ gg)
{
    __shared__ float2 hbuf[8][64];   // 4 KB
    __shared__ float2 w16[16];

    const int b   = blockIdx.x >> 3;
    const int n2c = (blockIdx.x & 7) * 64;
    const int tid = threadIdx.x;

    if (tid < 16) {
        float tn = -(float)tid * 0.0625f;   // -t/16 turns
        w16[tid] = make_float2(__builtin_amdgcn_cosf(tn),
                               __builtin_amdgcn_sinf(tn));
    }
    if (tid < 512) {
        int r   = tid >> 6;
        int n2l = tid & 63;
        int fidx = n2c + n2l + 512 * r;            // in [0,4096)
        float inv = deconv_signed(fidx);           // includes (-1)^j sign
        hbuf[r][n2l] = make_float2(fr[b * NMODES + fidx] * inv,
                                   fi[b * NMODES + fidx] * inv);
    }
    __syncthreads();

    const int k1  = tid >> 6;
    const int n2l = tid & 63;
    const int n2  = n2c + n2l;

    float2 acc = make_float2(0.0f, 0.0f);
#pragma unroll
    for (int r = 0; r < 8; ++r) {
        float2 w = w16[((r + 4) * k1) & 15];
        float2 h = hbuf[r][n2l];
        acc.x = fmaf(h.x, w.x, fmaf(-h.y, w.y, acc.x));
        acc.y = fmaf(h.x, w.y, fmaf( h.y, w.x, acc.y));
    }
    // big twiddle W8192^{n2*k1}: turns = -(n2*k1)/8192, in (-1, 0]
    float tn = -(float)(n2 * k1) * 1.220703125e-4f;
    float2 tw = make_float2(__builtin_amdgcn_cosf(tn),
                            __builtin_amdgcn_sinf(tn));
    gg[b * NGRID + k1 + 16 * n2] = cmul(acc, tw);
}

// ---------------------------------------------------------------------------
// Four-step FFT, step 3.  Block (b,k1): read gg[b][k1+16j] (j=0..511) into
// LDS bit-reversed, 9 DIT stages, write g[b][k1+16*k2'] = (-1)^k1 * X
// back to the SAME slot set (in-place per block; sets disjoint mod 16).
// ---------------------------------------------------------------------------
__global__ __launch_bounds__(256) void nfft_f2_kernel(float2* __restrict__ g)
{
    __shared__ float2 buf[512];      // 4 KB
    const int b   = blockIdx.x >> 4;
    const int k1  = blockIdx.x & 15;
    const int tid = threadIdx.x;

    float2* base = g + b * NGRID + k1;
#pragma unroll
    for (int ii = 0; ii < 2; ++ii) {
        int j  = tid + ii * 256;
        int rb = (int)(__brev((unsigned)j) >> 23);   // 9-bit reversal
        buf[rb] = base[16 * j];
    }
    __syncthreads();

    for (int s = 0; s <= 8; ++s) {
        const int   half = 1 << s;
        const float tscl = -0.5f / (float)half;      // turns per pos
        int i   = tid;                               // 256 butterflies
        int pos = i & (half - 1);
        int idx = ((i ^ pos) << 1) | pos;
        float sn = __builtin_amdgcn_sinf(tscl * (float)pos);
        float cs = __builtin_amdgcn_cosf(tscl * (float)pos);
        float2 a = buf[idx];
        float2 t = buf[idx + half];
        float2 bt = make_float2(t.x * cs - t.y * sn,
                                t.x * sn + t.y * cs);
        buf[idx]        = make_float2(a.x + bt.x, a.y + bt.y);
        buf[idx + half] = make_float2(a.x - bt.x, a.y - bt.y);
        __syncthreads();
    }

    const float sgn = (k1 & 1) ? -1.0f : 1.0f;
#pragma unroll
    for (int ii = 0; ii < 2; ++ii) {
        int j = tid + ii * 256;
        float2 v = buf[j];
        base[16 * j] = make_float2(v.x * sgn, v.y * sgn);
    }
}

// ---------------------------------------------------------------------------
// Kernel B (byte-identical to proven R7): stage one batch's g (64 KB, float4
// loads), interpolate 4096 points per block. 8 contiguous taps.
// ---------------------------------------------------------------------------
__global__ __launch_bounds__(1024) void nfft_interp_kernel(
    const float* __restrict__ x, const float2* __restrict__ g,
    float* __restrict__ out, int cplx)
{
    __shared__ float2 gl[NGRID];     // 64 KB
    const int b   = blockIdx.x >> 5;
    const int blk = blockIdx.x & 31;

    const float4* gs = (const float4*)(g + b * NGRID);
    float4*       gd = (float4*)gl;
    for (int i = threadIdx.x; i < NGRID / 2; i += 1024) gd[i] = gs[i];
    __syncthreads();

    const int base = b * NPTS + blk * 4096;
    for (int p = threadIdx.x; p < 4096; p += 1024) {
        float xv   = x[base + p];
        float fl   = xv * 8192.0f;                 // exact (2^13 scale)
        int   c    = (int)ceilf(fl);
        float frac = (float)c - fl;                // in [0,1)
        int   wr0  = (c + 4092 + 8192) & (NGRID - 1);  // (c-4+n/2) mod n
        float re = 0.0f, im = 0.0f;
#pragma unroll
        for (int l = 0; l < 8; ++l) {
            float u    = (float)(4 - l) - frac;    // n*x - ind
            float arg2 = 16.0f - u * u;            // m^2 - u^2
            float w    = 0.0f;
            if (arg2 > 0.0f) {                     // NaN / arg==0 -> 0
                float r   = rsqrtf(arg2);          // 1/arg
                float arg = arg2 * r;              // arg
                float z   = 4.71238898038468986f * arg;
                float ez  = __expf(z);
                float em  = __expf(-z);
                w = (ez - em) * 0.15915494309189533577f * r;  // sinh/(pi*arg)
            }
            float2 gv = gl[(wr0 + l) & (NGRID - 1)];
            re = fmaf(w, gv.x, re);
            im = fmaf(w, gv.y, im);
        }
        if (cplx) ((float2*)out)[base + p] = make_float2(re, im);
        else      out[base + p] = re;
    }
}

// ---------------------------------------------------------------------------
// Fallback: fully fused single kernel (proven in R4/R7) if d_ws too small.
// ---------------------------------------------------------------------------
__global__ __launch_bounds__(1024) void nfft_fused_kernel(
    const float* __restrict__ x, const float* __restrict__ fr,
    const float* __restrict__ fi, float* __restrict__ out, int cplx)
{
    __shared__ float2 buf[NGRID];
    const int b   = blockIdx.x >> 5;
    const int blk = blockIdx.x & 31;
    const int tid = threadIdx.x;

    for (int j = tid; j < NGRID; j += 1024) {
        float2 v = make_float2(0.0f, 0.0f);
        if (j >= 2048 && j < 6144) {
            int fidx = j - 2048;
            float inv = deconv_signed(fidx);
            v.x = fr[b * NMODES + fidx] * inv;
            v.y = fi[b * NMODES + fidx] * inv;
        }
        buf[j] = v;
    }
    __syncthreads();

    for (int s = 12; s >= 0; --s) {
        const int   half = 1 << s;
        const float tscl = -0.5f / (float)half;
#pragma unroll
        for (int ii = 0; ii < 4; ++ii) {
            int i = tid + ii * 1024;
            int pos = i & (half - 1);
            int idx = ((i ^ pos) << 1) | pos;
            float sn = __builtin_amdgcn_sinf(tscl * (float)pos);
            float cs = __builtin_amdgcn_cosf(tscl * (float)pos);
            float2 a = buf[idx];
            float2 c = buf[idx + half];
            buf[idx] = make_float2(a.x + c.x, a.y + c.y);
            float2 d = make_float2(a.x - c.x, a.y - c.y);
            buf[idx + half] = make_float2(d.x * cs - d.y * sn,
                                          d.x * sn + d.y * cs);
        }
        __syncthreads();
    }

    const int base = b * NPTS + blk * 4096;
    for (int p = tid; p < 4096; p += 1024) {
        float xv   = x[base + p];
        float fl   = xv * 8192.0f;
        int   c    = (int)ceilf(fl);
        float frac = (float)c - fl;
        float re = 0.0f, im = 0.0f;
#pragma unroll
        for (int l = 0; l < 8; ++l) {
            int   ind  = c - 4 + l;
            float u    = (float)(4 - l) - frac;
            float arg2 = 16.0f - u * u;
            float w    = 0.0f;
            if (arg2 > 0.0f) {
                float r   = rsqrtf(arg2);
                float arg = arg2 * r;
                float z   = 4.71238898038468986f * arg;
                w = (__expf(z) - __expf(-z)) * 0.15915494309189533577f * r;
            }
            if (ind & 1) w = -w;
            int wr = (ind + 4096) & (NGRID - 1);
            int rb = (int)(__brev((unsigned)wr) >> 19);
            float2 gv = buf[rb];
            re = fmaf(w, gv.x, re);
            im = fmaf(w, gv.y, im);
        }
        if (cplx) ((float2*)out)[base + p] = make_float2(re, im);
        else      out[base + p] = re;
    }
}

extern "C" void kernel_launch(void* const* d_in, const int* in_sizes, int n_in,
                              void* d_out, int out_size, void* d_ws, size_t ws_size,
                              hipStream_t stream) {
    (void)in_sizes; (void)n_in;
    const float* x  = (const float*)d_in[0];
    const float* fr = (const float*)d_in[1];
    const float* fi = (const float*)d_in[2];

    const int cplx = (out_size >= BATCH * NPTS * 2) ? 1 : 0;
    const size_t g_bytes = (size_t)BATCH * NGRID * sizeof(float2);  // 1 MB

    if (ws_size >= g_bytes) {
        float2* g = (float2*)d_ws;
        nfft_f1_kernel<<<BATCH * 8, 1024, 0, stream>>>(fr, fi, g);
        nfft_f2_kernel<<<BATCH * 16, 256, 0, stream>>>(g);
        nfft_interp_kernel<<<BATCH * 32, 1024, 0, stream>>>(
            x, g, (float*)d_out, cplx);
    } else {
        nfft_fused_kernel<<<BATCH * 32, 1024, 0, stream>>>(
            x, fr, fi, (float*)d_out, cplx);
    }
}

// Round 10
// 28.128 us; speedup vs baseline: 1.2795x; 1.0477x over previous
//
#include <hip/hip_runtime.h>
#include <hip/hip_fp16.h>
#include <math.h>

#define NMODES 4096
#define NGRID  8192
#define BATCH  16
#define NPTS   131072
#define GSCALE 1048576.0f          // 2^20 (exact)
#define OSCALE 1.5178830414797062e-07f  // 1/(2*pi*2^20)

__device__ __forceinline__ float2 cmul(float2 a, float2 b) {
    return make_float2(a.x * b.x - a.y * b.y, a.x * b.y + a.y * b.x);
}

// ---------------------------------------------------------------------------
// Deconvolution factor: (-1)^fidx / phi_hat(fidx), I0 asymptotic (z~18).
// ---------------------------------------------------------------------------
__device__ __forceinline__ float deconv_signed(int fidx) {
    float k = (float)(fidx - 2048);
    float t = k * 7.66990393942820614e-4f;                 // 2*pi*k/n
    float z = 4.0f * sqrtf(22.2066099024510563f - t * t);  // m*sqrt(b^2-t^2)
    float iz = 1.0f / z;
    float p  = 1.0f + iz * (0.125f + iz * (0.0703125f +
               iz * (0.0732421875f + iz * 0.112152099609375f)));
    float phi = __expf(z) * p * rsqrtf(6.28318530717958648f * z);
    float s = (fidx & 1) ? -1.0f : 1.0f;
    return s / phi;
}

// ---------------------------------------------------------------------------
// Four-step FFT, step 1+2 (unchanged from R9, green).
// ---------------------------------------------------------------------------
__global__ __launch_bounds__(1024) void nfft_f1_kernel(
    const float* __restrict__ fr, const float* __restrict__ fi,
    float2* __restrict__ gg)
{
    __shared__ float2 hbuf[8][64];   // 4 KB
    __shared__ float2 w16[16];

    const int b   = blockIdx.x >> 3;
    const int n2c = (blockIdx.x & 7) * 64;
    const int tid = threadIdx.x;

    if (tid < 16) {
        float tn = -(float)tid * 0.0625f;   // -t/16 turns
        w16[tid] = make_float2(__builtin_amdgcn_cosf(tn),
                               __builtin_amdgcn_sinf(tn));
    }
    if (tid < 512) {
        int r   = tid >> 6;
        int n2l = tid & 63;
        int fidx = n2c + n2l + 512 * r;            // in [0,4096)
        float inv = deconv_signed(fidx);           // includes (-1)^j sign
        hbuf[r][n2l] = make_float2(fr[b * NMODES + fidx] * inv,
                                   fi[b * NMODES + fidx] * inv);
    }
    __syncthreads();

    const int k1  = tid >> 6;
    const int n2l = tid & 63;
    const int n2  = n2c + n2l;

    float2 acc = make_float2(0.0f, 0.0f);
#pragma unroll
    for (int r = 0; r < 8; ++r) {
        float2 w = w16[((r + 4) * k1) & 15];
        float2 h = hbuf[r][n2l];
        acc.x = fmaf(h.x, w.x, fmaf(-h.y, w.y, acc.x));
        acc.y = fmaf(h.x, w.y, fmaf( h.y, w.x, acc.y));
    }
    float tn = -(float)(n2 * k1) * 1.220703125e-4f;   // -(n2*k1)/8192 turns
    float2 tw = make_float2(__builtin_amdgcn_cosf(tn),
                            __builtin_amdgcn_sinf(tn));
    gg[b * NGRID + k1 + 16 * n2] = cmul(acc, tw);
}

// ---------------------------------------------------------------------------
// Four-step FFT, step 3 (unchanged from R9, green).
// ---------------------------------------------------------------------------
__global__ __launch_bounds__(256) void nfft_f2_kernel(float2* __restrict__ g)
{
    __shared__ float2 buf[512];      // 4 KB
    const int b   = blockIdx.x >> 4;
    const int k1  = blockIdx.x & 15;
    const int tid = threadIdx.x;

    float2* base = g + b * NGRID + k1;
#pragma unroll
    for (int ii = 0; ii < 2; ++ii) {
        int j  = tid + ii * 256;
        int rb = (int)(__brev((unsigned)j) >> 23);   // 9-bit reversal
        buf[rb] = base[16 * j];
    }
    __syncthreads();

    for (int s = 0; s <= 8; ++s) {
        const int   half = 1 << s;
        const float tscl = -0.5f / (float)half;      // turns per pos
        int i   = tid;
        int pos = i & (half - 1);
        int idx = ((i ^ pos) << 1) | pos;
        float sn = __builtin_amdgcn_sinf(tscl * (float)pos);
        float cs = __builtin_amdgcn_cosf(tscl * (float)pos);
        float2 a = buf[idx];
        float2 t = buf[idx + half];
        float2 bt = make_float2(t.x * cs - t.y * sn,
                                t.x * sn + t.y * cs);
        buf[idx]        = make_float2(a.x + bt.x, a.y + bt.y);
        buf[idx + half] = make_float2(a.x - bt.x, a.y - bt.y);
        __syncthreads();
    }

    const float sgn = (k1 & 1) ? -1.0f : 1.0f;
#pragma unroll
    for (int ii = 0; ii < 2; ++ii) {
        int j = tid + ii * 256;
        float2 v = buf[j];
        base[16 * j] = make_float2(v.x * sgn, v.y * sgn);
    }
}

// ---------------------------------------------------------------------------
// Kernel B: fp16 cell-packed g (half2=(re,im)*2^20 per cell, 32 KB + 8 wrap
// cells so tap reads never need a mask). Window = e^z/(2*pi*arg) (e^{-z}
// dropped: rel err e^{-2z}, output err <= ~0.01). 4 pts/thread, float4 IO.
// ---------------------------------------------------------------------------
__global__ __launch_bounds__(1024) void nfft_interp_kernel(
    const float* __restrict__ x, const float2* __restrict__ g,
    float* __restrict__ out, int cplx)
{
    __shared__ __half2 gl16[NGRID + 8];   // 32 KB + wrap pad

    const int b   = blockIdx.x >> 5;
    const int blk = blockIdx.x & 31;
    const int tid = threadIdx.x;

    const float4* gs = (const float4*)(g + b * NGRID);
    for (int i = tid; i < NGRID / 2; i += 1024) {
        float4 v = gs[i];
        gl16[2 * i]     = __floats2half2_rn(v.x * GSCALE, v.y * GSCALE);
        gl16[2 * i + 1] = __floats2half2_rn(v.z * GSCALE, v.w * GSCALE);
    }
    if (tid < 8) {   // wrap cells: gl16[8192+i] = g[i]
        float2 v = g[b * NGRID + tid];
        gl16[NGRID + tid] = __floats2half2_rn(v.x * GSCALE, v.y * GSCALE);
    }
    __syncthreads();

    const int base = b * NPTS + blk * 4096;
    const float4 xv4 = ((const float4*)(x + base))[tid];
    float outre[4], outim[4];

#pragma unroll
    for (int q = 0; q < 4; ++q) {
        float xv = (q == 0) ? xv4.x : (q == 1) ? xv4.y : (q == 2) ? xv4.z : xv4.w;
        float fl   = xv * 8192.0f;                 // exact (2^13 scale)
        float cf   = ceilf(fl);
        int   c    = (int)cf;
        float frac = cf - fl;                      // [0,1)
        int   wr0  = (c + 12284) & (NGRID - 1);    // (c-4+n/2) mod n
        float re = 0.0f, im = 0.0f;
#pragma unroll
        for (int l = 0; l < 8; ++l) {
            float u    = (float)(4 - l) - frac;    // n*x - ind
            float arg2 = fmaf(-u, u, 16.0f);       // m^2 - u^2
            float r    = rsqrtf(arg2);             // 1/arg
            float z    = arg2 * r * 4.71238898038468986f;  // b*arg
            float w    = __expf(z) * r;            // ~ 2*sinh(z)/arg (scaled later)
            w = (arg2 > 0.0f) ? w : 0.0f;          // NaN / arg==0 -> 0
            float2 gv = __half22float2(gl16[wr0 + l]);
            re = fmaf(w, gv.x, re);
            im = fmaf(w, gv.y, im);
        }
        outre[q] = re * OSCALE;
        outim[q] = im * OSCALE;
    }

    if (cplx) {
        float2* o = ((float2*)out) + base + tid * 4;
        o[0] = make_float2(outre[0], outim[0]);
        o[1] = make_float2(outre[1], outim[1]);
        o[2] = make_float2(outre[2], outim[2]);
        o[3] = make_float2(outre[3], outim[3]);
    } else {
        ((float4*)(out + base))[tid] =
            make_float4(outre[0], outre[1], outre[2], outre[3]);
    }
}

// ---------------------------------------------------------------------------
// Fallback: fully fused single kernel (proven R4/R7) if d_ws too small.
// ---------------------------------------------------------------------------
__global__ __launch_bounds__(1024) void nfft_fused_kernel(
    const float* __restrict__ x, const float* __restrict__ fr,
    const float* __restrict__ fi, float* __restrict__ out, int cplx)
{
    __shared__ float2 buf[NGRID];
    const int b   = blockIdx.x >> 5;
    const int blk = blockIdx.x & 31;
    const int tid = threadIdx.x;

    for (int j = tid; j < NGRID; j += 1024) {
        float2 v = make_float2(0.0f, 0.0f);
        if (j >= 2048 && j < 6144) {
            int fidx = j - 2048;
            float inv = deconv_signed(fidx);
            v.x = fr[b * NMODES + fidx] * inv;
            v.y = fi[b * NMODES + fidx] * inv;
        }
        buf[j] = v;
    }
    __syncthreads();

    for (int s = 12; s >= 0; --s) {
        const int   half = 1 << s;
        const float tscl = -0.5f / (float)half;
#pragma unroll
        for (int ii = 0; ii < 4; ++ii) {
            int i = tid + ii * 1024;
            int pos = i & (half - 1);
            int idx = ((i ^ pos) << 1) | pos;
            float sn = __builtin_amdgcn_sinf(tscl * (float)pos);
            float cs = __builtin_amdgcn_cosf(tscl * (float)pos);
            float2 a = buf[idx];
            float2 c = buf[idx + half];
            buf[idx] = make_float2(a.x + c.x, a.y + c.y);
            float2 d = make_float2(a.x - c.x, a.y - c.y);
            buf[idx + half] = make_float2(d.x * cs - d.y * sn,
                                          d.x * sn + d.y * cs);
        }
        __syncthreads();
    }

    const int base = b * NPTS + blk * 4096;
    for (int p = tid; p < 4096; p += 1024) {
        float xv   = x[base + p];
        float fl   = xv * 8192.0f;
        int   c    = (int)ceilf(fl);
        float frac = (float)c - fl;
        float re = 0.0f, im = 0.0f;
#pragma unroll
        for (int l = 0; l < 8; ++l) {
            int   ind  = c - 4 + l;
            float u    = (float)(4 - l) - frac;
            float arg2 = 16.0f - u * u;
            float w    = 0.0f;
            if (arg2 > 0.0f) {
                float r   = rsqrtf(arg2);
                float arg = arg2 * r;
                float z   = 4.71238898038468986f * arg;
                w = (__expf(z) - __expf(-z)) * 0.15915494309189533577f * r;
            }
            if (ind & 1) w = -w;
            int wr = (ind + 4096) & (NGRID - 1);
            int rb = (int)(__brev((unsigned)wr) >> 19);
            float2 gv = buf[rb];
            re = fmaf(w, gv.x, re);
            im = fmaf(w, gv.y, im);
        }
        if (cplx) ((float2*)out)[base + p] = make_float2(re, im);
        else      out[base + p] = re;
    }
}

extern "C" void kernel_launch(void* const* d_in, const int* in_sizes, int n_in,
                              void* d_out, int out_size, void* d_ws, size_t ws_size,
                              hipStream_t stream) {
    (void)in_sizes; (void)n_in;
    const float* x  = (const float*)d_in[0];
    const float* fr = (const float*)d_in[1];
    const float* fi = (const float*)d_in[2];

    const int cplx = (out_size >= BATCH * NPTS * 2) ? 1 : 0;
    const size_t g_bytes = (size_t)BATCH * NGRID * sizeof(float2);  // 1 MB

    if (ws_size >= g_bytes) {
        float2* g = (float2*)d_ws;
        nfft_f1_kernel<<<BATCH * 8, 1024, 0, stream>>>(fr, fi, g);
        nfft_f2_kernel<<<BATCH * 16, 256, 0, stream>>>(g);
        nfft_interp_kernel<<<BATCH * 32, 1024, 0, stream>>>(
            x, g, (float*)d_out, cplx);
    } else {
        nfft_fused_kernel<<<BATCH * 32, 1024, 0, stream>>>(
            x, fr, fi, (float*)d_out, cplx);
    }
}

// Round 11
// 25.051 us; speedup vs baseline: 1.4367x; 1.1228x over previous
//
#include <hip/hip_runtime.h>
#include <hip/hip_fp16.h>
#include <math.h>

#define NMODES 4096
#define NGRID  8192
#define BATCH  16
#define NPTS   131072
#define GSCALE 1048576.0f               // 2^20 (exact)
#define OSCALE 1.5178830414797062e-07f  // 1/(2*pi*2^20)

__device__ __forceinline__ float2 cmul(float2 a, float2 b) {
    return make_float2(a.x * b.x - a.y * b.y, a.x * b.y + a.y * b.x);
}

// ---------------------------------------------------------------------------
// Deconvolution factor: (-1)^fidx / phi_hat(fidx), I0 asymptotic (z~18).
// ---------------------------------------------------------------------------
__device__ __forceinline__ float deconv_signed(int fidx) {
    float k = (float)(fidx - 2048);
    float t = k * 7.66990393942820614e-4f;                 // 2*pi*k/n
    float z = 4.0f * sqrtf(22.2066099024510563f - t * t);  // m*sqrt(b^2-t^2)
    float iz = 1.0f / z;
    float p  = 1.0f + iz * (0.125f + iz * (0.0703125f +
               iz * (0.0732421875f + iz * 0.112152099609375f)));
    float phi = __expf(z) * p * rsqrtf(6.28318530717958648f * z);
    float s = (fidx & 1) ? -1.0f : 1.0f;
    return s / phi;
}

// ---------------------------------------------------------------------------
// Merged four-step FFT: one block per (batch, k1).  Load full f_hat*inv into
// LDS (16x redundant per batch, cheap), compute the k1-row
//   C[n2] = sum_{r=0..7} h[n2+512r] * W16^{(r+4)k1},   * W8192^{n2*k1},
// bit-rev scatter, 9 DIT stages, write g[k1+16*k2] = (-1)^{k1} * X[k2].
// Same index algebra as the green R9 f1/f2 pair, relocated into one kernel.
// ---------------------------------------------------------------------------
__global__ __launch_bounds__(256) void nfft_fft_kernel(
    const float* __restrict__ fr, const float* __restrict__ fi,
    float2* __restrict__ g)
{
    __shared__ float2 hbuf[NMODES];  // 32 KB
    __shared__ float2 fbuf[512];     // 4 KB
    __shared__ float2 w16[16];

    const int b   = blockIdx.x >> 4;
    const int k1  = blockIdx.x & 15;
    const int tid = threadIdx.x;

    if (tid < 16) {
        float tn = -(float)tid * 0.0625f;   // -t/16 turns
        w16[tid] = make_float2(__builtin_amdgcn_cosf(tn),
                               __builtin_amdgcn_sinf(tn));
    }
#pragma unroll
    for (int i = 0; i < 16; ++i) {          // coalesced: lanes consecutive
        int fidx = tid + i * 256;
        float inv = deconv_signed(fidx);    // includes (-1)^j sign
        hbuf[fidx] = make_float2(fr[b * NMODES + fidx] * inv,
                                 fi[b * NMODES + fidx] * inv);
    }
    __syncthreads();

#pragma unroll
    for (int hi = 0; hi < 2; ++hi) {
        int n2 = tid + hi * 256;
        float2 acc = make_float2(0.0f, 0.0f);
#pragma unroll
        for (int r = 0; r < 8; ++r) {
            float2 w = w16[((r + 4) * k1) & 15];
            float2 h = hbuf[n2 + 512 * r];
            acc.x = fmaf(h.x, w.x, fmaf(-h.y, w.y, acc.x));
            acc.y = fmaf(h.x, w.y, fmaf( h.y, w.x, acc.y));
        }
        float tn = -(float)(n2 * k1) * 1.220703125e-4f;  // -(n2*k1)/8192 turns
        float2 tw = make_float2(__builtin_amdgcn_cosf(tn),
                                __builtin_amdgcn_sinf(tn));
        int rb = (int)(__brev((unsigned)n2) >> 23);      // 9-bit reversal
        fbuf[rb] = cmul(acc, tw);
    }
    __syncthreads();

    for (int s = 0; s <= 8; ++s) {
        const int   half = 1 << s;
        const float tscl = -0.5f / (float)half;          // turns per pos
        int pos = tid & (half - 1);
        int idx = ((tid ^ pos) << 1) | pos;
        float sn = __builtin_amdgcn_sinf(tscl * (float)pos);
        float cs = __builtin_amdgcn_cosf(tscl * (float)pos);
        float2 a = fbuf[idx];
        float2 t = fbuf[idx + half];
        float2 bt = make_float2(t.x * cs - t.y * sn,
                                t.x * sn + t.y * cs);
        fbuf[idx]        = make_float2(a.x + bt.x, a.y + bt.y);
        fbuf[idx + half] = make_float2(a.x - bt.x, a.y - bt.y);
        __syncthreads();
    }

    const float sgn = (k1 & 1) ? -1.0f : 1.0f;
    float2* base = g + b * NGRID + k1;
#pragma unroll
    for (int ii = 0; ii < 2; ++ii) {
        int j = tid + ii * 256;
        float2 v = fbuf[j];
        base[16 * j] = make_float2(v.x * sgn, v.y * sgn);
    }
}

// ---------------------------------------------------------------------------
// Kernel B (byte-identical to R10, green): fp16 cell-packed g in LDS
// (half2=(re,im)*2^20, 32 KB + 8 wrap cells), window = e^z/(2*pi*arg),
// 4 pts/thread, float4 IO.
// ---------------------------------------------------------------------------
__global__ __launch_bounds__(1024) void nfft_interp_kernel(
    const float* __restrict__ x, const float2* __restrict__ g,
    float* __restrict__ out, int cplx)
{
    __shared__ __half2 gl16[NGRID + 8];   // 32 KB + wrap pad

    const int b   = blockIdx.x >> 5;
    const int blk = blockIdx.x & 31;
    const int tid = threadIdx.x;

    const float4* gs = (const float4*)(g + b * NGRID);
    for (int i = tid; i < NGRID / 2; i += 1024) {
        float4 v = gs[i];
        gl16[2 * i]     = __floats2half2_rn(v.x * GSCALE, v.y * GSCALE);
        gl16[2 * i + 1] = __floats2half2_rn(v.z * GSCALE, v.w * GSCALE);
    }
    if (tid < 8) {   // wrap cells: gl16[8192+i] = g[i]
        float2 v = g[b * NGRID + tid];
        gl16[NGRID + tid] = __floats2half2_rn(v.x * GSCALE, v.y * GSCALE);
    }
    __syncthreads();

    const int base = b * NPTS + blk * 4096;
    const float4 xv4 = ((const float4*)(x + base))[tid];
    float outre[4], outim[4];

#pragma unroll
    for (int q = 0; q < 4; ++q) {
        float xv = (q == 0) ? xv4.x : (q == 1) ? xv4.y : (q == 2) ? xv4.z : xv4.w;
        float fl   = xv * 8192.0f;                 // exact (2^13 scale)
        float cf   = ceilf(fl);
        int   c    = (int)cf;
        float frac = cf - fl;                      // [0,1)
        int   wr0  = (c + 12284) & (NGRID - 1);    // (c-4+n/2) mod n
        float re = 0.0f, im = 0.0f;
#pragma unroll
        for (int l = 0; l < 8; ++l) {
            float u    = (float)(4 - l) - frac;    // n*x - ind
            float arg2 = fmaf(-u, u, 16.0f);       // m^2 - u^2
            float r    = rsqrtf(arg2);             // 1/arg
            float z    = arg2 * r * 4.71238898038468986f;  // b*arg
            float w    = __expf(z) * r;            // ~ 2*sinh(z)/arg (scaled later)
            w = (arg2 > 0.0f) ? w : 0.0f;          // NaN / arg==0 -> 0
            float2 gv = __half22float2(gl16[wr0 + l]);
            re = fmaf(w, gv.x, re);
            im = fmaf(w, gv.y, im);
        }
        outre[q] = re * OSCALE;
        outim[q] = im * OSCALE;
    }

    if (cplx) {
        float2* o = ((float2*)out) + base + tid * 4;
        o[0] = make_float2(outre[0], outim[0]);
        o[1] = make_float2(outre[1], outim[1]);
        o[2] = make_float2(outre[2], outim[2]);
        o[3] = make_float2(outre[3], outim[3]);
    } else {
        ((float4*)(out + base))[tid] =
            make_float4(outre[0], outre[1], outre[2], outre[3]);
    }
}

// ---------------------------------------------------------------------------
// Fallback: fully fused single kernel (proven R4/R7) if d_ws too small.
// ---------------------------------------------------------------------------
__global__ __launch_bounds__(1024) void nfft_fused_kernel(
    const float* __restrict__ x, const float* __restrict__ fr,
    const float* __restrict__ fi, float* __restrict__ out, int cplx)
{
    __shared__ float2 buf[NGRID];
    const int b   = blockIdx.x >> 5;
    const int blk = blockIdx.x & 31;
    const int tid = threadIdx.x;

    for (int j = tid; j < NGRID; j += 1024) {
        float2 v = make_float2(0.0f, 0.0f);
        if (j >= 2048 && j < 6144) {
            int fidx = j - 2048;
            float inv = deconv_signed(fidx);
            v.x = fr[b * NMODES + fidx] * inv;
            v.y = fi[b * NMODES + fidx] * inv;
        }
        buf[j] = v;
    }
    __syncthreads();

    for (int s = 12; s >= 0; --s) {
        const int   half = 1 << s;
        const float tscl = -0.5f / (float)half;
#pragma unroll
        for (int ii = 0; ii < 4; ++ii) {
            int i = tid + ii * 1024;
            int pos = i & (half - 1);
            int idx = ((i ^ pos) << 1) | pos;
            float sn = __builtin_amdgcn_sinf(tscl * (float)pos);
            float cs = __builtin_amdgcn_cosf(tscl * (float)pos);
            float2 a = buf[idx];
            float2 c = buf[idx + half];
            buf[idx] = make_float2(a.x + c.x, a.y + c.y);
            float2 d = make_float2(a.x - c.x, a.y - c.y);
            buf[idx + half] = make_float2(d.x * cs - d.y * sn,
                                          d.x * sn + d.y * cs);
        }
        __syncthreads();
    }

    const int base = b * NPTS + blk * 4096;
    for (int p = tid; p < 4096; p += 1024) {
        float xv   = x[base + p];
        float fl   = xv * 8192.0f;
        int   c    = (int)ceilf(fl);
        float frac = (float)c - fl;
        float re = 0.0f, im = 0.0f;
#pragma unroll
        for (int l = 0; l < 8; ++l) {
            int   ind  = c - 4 + l;
            float u    = (float)(4 - l) - frac;
            float arg2 = 16.0f - u * u;
            float w    = 0.0f;
            if (arg2 > 0.0f) {
                float r   = rsqrtf(arg2);
                float arg = arg2 * r;
                float z   = 4.71238898038468986f * arg;
                w = (__expf(z) - __expf(-z)) * 0.15915494309189533577f * r;
            }
            if (ind & 1) w = -w;
            int wr = (ind + 4096) & (NGRID - 1);
            int rb = (int)(__brev((unsigned)wr) >> 19);
            float2 gv = buf[rb];
            re = fmaf(w, gv.x, re);
            im = fmaf(w, gv.y, im);
        }
        if (cplx) ((float2*)out)[base + p] = make_float2(re, im);
        else      out[base + p] = re;
    }
}

extern "C" void kernel_launch(void* const* d_in, const int* in_sizes, int n_in,
                              void* d_out, int out_size, void* d_ws, size_t ws_size,
                              hipStream_t stream) {
    (void)in_sizes; (void)n_in;
    const float* x  = (const float*)d_in[0];
    const float* fr = (const float*)d_in[1];
    const float* fi = (const float*)d_in[2];

    const int cplx = (out_size >= BATCH * NPTS * 2) ? 1 : 0;
    const size_t g_bytes = (size_t)BATCH * NGRID * sizeof(float2);  // 1 MB

    if (ws_size >= g_bytes) {
        float2* g = (float2*)d_ws;
        nfft_fft_kernel<<<BATCH * 16, 256, 0, stream>>>(fr, fi, g);
        nfft_interp_kernel<<<BATCH * 32, 1024, 0, stream>>>(
            x, g, (float*)d_out, cplx);
    } else {
        nfft_fused_kernel<<<BATCH * 32, 1024, 0, stream>>>(
            x, fr, fi, (float*)d_out, cplx);
    }
}

// Round 12
// 22.114 us; speedup vs baseline: 1.6275x; 1.1328x over previous
//
#include <hip/hip_runtime.h>
#include <hip/hip_fp16.h>
#include <math.h>

#define NMODES 4096
#define NGRID  8192
#define BATCH  16
#define NPTS   131072
#define GSTRIDE 8200                    // 8192 + 8 wrap cells, u32 each
#define GSCALE 1048576.0f               // 2^20 (exact)
#define OSCALE 1.5178830414797062e-07f  // 1/(2*pi*2^20)

__device__ __forceinline__ float2 cmul(float2 a, float2 b) {
    return make_float2(a.x * b.x - a.y * b.y, a.x * b.y + a.y * b.x);
}

// ---------------------------------------------------------------------------
// Deconvolution factor: (-1)^fidx / phi_hat(fidx), I0 asymptotic (z~18).
// ---------------------------------------------------------------------------
__device__ __forceinline__ float deconv_signed(int fidx) {
    float k = (float)(fidx - 2048);
    float t = k * 7.66990393942820614e-4f;                 // 2*pi*k/n
    float z = 4.0f * sqrtf(22.2066099024510563f - t * t);  // m*sqrt(b^2-t^2)
    float iz = 1.0f / z;
    float p  = 1.0f + iz * (0.125f + iz * (0.0703125f +
               iz * (0.0732421875f + iz * 0.112152099609375f)));
    float phi = __expf(z) * p * rsqrtf(6.28318530717958648f * z);
    float s = (fidx & 1) ? -1.0f : 1.0f;
    return s / phi;
}

// ---------------------------------------------------------------------------
// Merged four-step FFT (index algebra identical to green R11), but the
// output is packed scaled fp16: g16[cell] = half2(re,im) * 2^20, plus 8
// wrap cells g16[8192+i] = g16[i] so interp taps never need a mod.
// One block per (batch, k1).
// ---------------------------------------------------------------------------
__global__ __launch_bounds__(256) void nfft_fft_kernel(
    const float* __restrict__ fr, const float* __restrict__ fi,
    __half2* __restrict__ g16)
{
    __shared__ float2 hbuf[NMODES];  // 32 KB
    __shared__ float2 fbuf[512];     // 4 KB
    __shared__ float2 w16[16];

    const int b   = blockIdx.x >> 4;
    const int k1  = blockIdx.x & 15;
    const int tid = threadIdx.x;

    if (tid < 16) {
        float tn = -(float)tid * 0.0625f;   // -t/16 turns
        w16[tid] = make_float2(__builtin_amdgcn_cosf(tn),
                               __builtin_amdgcn_sinf(tn));
    }
#pragma unroll
    for (int i = 0; i < 16; ++i) {          // coalesced: lanes consecutive
        int fidx = tid + i * 256;
        float inv = deconv_signed(fidx);    // includes (-1)^j sign
        hbuf[fidx] = make_float2(fr[b * NMODES + fidx] * inv,
                                 fi[b * NMODES + fidx] * inv);
    }
    __syncthreads();

#pragma unroll
    for (int hi = 0; hi < 2; ++hi) {
        int n2 = tid + hi * 256;
        float2 acc = make_float2(0.0f, 0.0f);
#pragma unroll
        for (int r = 0; r < 8; ++r) {
            float2 w = w16[((r + 4) * k1) & 15];
            float2 h = hbuf[n2 + 512 * r];
            acc.x = fmaf(h.x, w.x, fmaf(-h.y, w.y, acc.x));
            acc.y = fmaf(h.x, w.y, fmaf( h.y, w.x, acc.y));
        }
        float tn = -(float)(n2 * k1) * 1.220703125e-4f;  // -(n2*k1)/8192 turns
        float2 tw = make_float2(__builtin_amdgcn_cosf(tn),
                                __builtin_amdgcn_sinf(tn));
        int rb = (int)(__brev((unsigned)n2) >> 23);      // 9-bit reversal
        fbuf[rb] = cmul(acc, tw);
    }
    __syncthreads();

    for (int s = 0; s <= 8; ++s) {
        const int   half = 1 << s;
        const float tscl = -0.5f / (float)half;          // turns per pos
        int pos = tid & (half - 1);
        int idx = ((tid ^ pos) << 1) | pos;
        float sn = __builtin_amdgcn_sinf(tscl * (float)pos);
        float cs = __builtin_amdgcn_cosf(tscl * (float)pos);
        float2 a = fbuf[idx];
        float2 t = fbuf[idx + half];
        float2 bt = make_float2(t.x * cs - t.y * sn,
                                t.x * sn + t.y * cs);
        fbuf[idx]        = make_float2(a.x + bt.x, a.y + bt.y);
        fbuf[idx + half] = make_float2(a.x - bt.x, a.y - bt.y);
        __syncthreads();
    }

    const float s2 = ((k1 & 1) ? -1.0f : 1.0f) * GSCALE;  // sign * 2^20
    __half2* base = g16 + b * GSTRIDE + k1;
#pragma unroll
    for (int ii = 0; ii < 2; ++ii) {
        int j = tid + ii * 256;
        float2 v = fbuf[j];
        base[16 * j] = __floats2half2_rn(v.x * s2, v.y * s2);
    }
    if (tid == 0 && k1 < 8) {   // wrap cell: cell k1 (=k1+16*0) duplicated
        float2 v = fbuf[0];
        g16[b * GSTRIDE + NGRID + k1] = __floats2half2_rn(v.x * s2, v.y * s2);
    }
}

// ---------------------------------------------------------------------------
// Interp: NO LDS, no barrier. Per-batch g16 is 32.8 KB (L1-resident; all
// batches L2-resident). 8 taps = 8 global_load_dword at compile-time
// offsets from one per-point base. Window = e^z/(2*pi*arg). 4 pts/thread.
// ---------------------------------------------------------------------------
__global__ __launch_bounds__(1024) void nfft_interp_kernel(
    const float* __restrict__ x, const __half2* __restrict__ g16,
    float* __restrict__ out, int cplx)
{
    const int b   = blockIdx.x >> 5;
    const int blk = blockIdx.x & 31;
    const int tid = threadIdx.x;

    const __half2* gb = g16 + b * GSTRIDE;
    const int base = b * NPTS + blk * 4096;
    const float4 xv4 = ((const float4*)(x + base))[tid];
    float outre[4], outim[4];

#pragma unroll
    for (int q = 0; q < 4; ++q) {
        float xv = (q == 0) ? xv4.x : (q == 1) ? xv4.y : (q == 2) ? xv4.z : xv4.w;
        float fl   = xv * 8192.0f;                 // exact (2^13 scale)
        float cf   = ceilf(fl);
        int   c    = (int)cf;
        float frac = cf - fl;                      // [0,1)
        int   wr0  = (c + 12284) & (NGRID - 1);    // (c-4+n/2) mod n
        const __half2* gp = gb + wr0;              // taps: gp[0..7] (pad covers +7)
        float re = 0.0f, im = 0.0f;
#pragma unroll
        for (int l = 0; l < 8; ++l) {
            float u    = (float)(4 - l) - frac;    // n*x - ind
            float arg2 = fmaf(-u, u, 16.0f);       // m^2 - u^2
            float r    = rsqrtf(arg2);             // 1/arg
            float z    = arg2 * r * 4.71238898038468986f;  // b*arg
            float w    = __expf(z) * r;            // ~2*sinh(z)/arg (scaled later)
            w = (arg2 > 0.0f) ? w : 0.0f;          // NaN / arg==0 -> 0
            float2 gv = __half22float2(gp[l]);
            re = fmaf(w, gv.x, re);
            im = fmaf(w, gv.y, im);
        }
        outre[q] = re * OSCALE;
        outim[q] = im * OSCALE;
    }

    if (cplx) {
        float2* o = ((float2*)out) + base + tid * 4;
        o[0] = make_float2(outre[0], outim[0]);
        o[1] = make_float2(outre[1], outim[1]);
        o[2] = make_float2(outre[2], outim[2]);
        o[3] = make_float2(outre[3], outim[3]);
    } else {
        ((float4*)(out + base))[tid] =
            make_float4(outre[0], outre[1], outre[2], outre[3]);
    }
}

// ---------------------------------------------------------------------------
// Fallback: fully fused single kernel (proven R4/R7) if d_ws too small.
// ---------------------------------------------------------------------------
__global__ __launch_bounds__(1024) void nfft_fused_kernel(
    const float* __restrict__ x, const float* __restrict__ fr,
    const float* __restrict__ fi, float* __restrict__ out, int cplx)
{
    __shared__ float2 buf[NGRID];
    const int b   = blockIdx.x >> 5;
    const int blk = blockIdx.x & 31;
    const int tid = threadIdx.x;

    for (int j = tid; j < NGRID; j += 1024) {
        float2 v = make_float2(0.0f, 0.0f);
        if (j >= 2048 && j < 6144) {
            int fidx = j - 2048;
            float inv = deconv_signed(fidx);
            v.x = fr[b * NMODES + fidx] * inv;
            v.y = fi[b * NMODES + fidx] * inv;
        }
        buf[j] = v;
    }
    __syncthreads();

    for (int s = 12; s >= 0; --s) {
        const int   half = 1 << s;
        const float tscl = -0.5f / (float)half;
#pragma unroll
        for (int ii = 0; ii < 4; ++ii) {
            int i = tid + ii * 1024;
            int pos = i & (half - 1);
            int idx = ((i ^ pos) << 1) | pos;
            float sn = __builtin_amdgcn_sinf(tscl * (float)pos);
            float cs = __builtin_amdgcn_cosf(tscl * (float)pos);
            float2 a = buf[idx];
            float2 c = buf[idx + half];
            buf[idx] = make_float2(a.x + c.x, a.y + c.y);
            float2 d = make_float2(a.x - c.x, a.y - c.y);
            buf[idx + half] = make_float2(d.x * cs - d.y * sn,
                                          d.x * sn + d.y * cs);
        }
        __syncthreads();
    }

    const int base = b * NPTS + blk * 4096;
    for (int p = tid; p < 4096; p += 1024) {
        float xv   = x[base + p];
        float fl   = xv * 8192.0f;
        int   c    = (int)ceilf(fl);
        float frac = (float)c - fl;
        float re = 0.0f, im = 0.0f;
#pragma unroll
        for (int l = 0; l < 8; ++l) {
            int   ind  = c - 4 + l;
            float u    = (float)(4 - l) - frac;
            float arg2 = 16.0f - u * u;
            float w    = 0.0f;
            if (arg2 > 0.0f) {
                float r   = rsqrtf(arg2);
                float arg = arg2 * r;
                float z   = 4.71238898038468986f * arg;
                w = (__expf(z) - __expf(-z)) * 0.15915494309189533577f * r;
            }
            if (ind & 1) w = -w;
            int wr = (ind + 4096) & (NGRID - 1);
            int rb = (int)(__brev((unsigned)wr) >> 19);
            float2 gv = buf[rb];
            re = fmaf(w, gv.x, re);
            im = fmaf(w, gv.y, im);
        }
        if (cplx) ((float2*)out)[base + p] = make_float2(re, im);
        else      out[base + p] = re;
    }
}

extern "C" void kernel_launch(void* const* d_in, const int* in_sizes, int n_in,
                              void* d_out, int out_size, void* d_ws, size_t ws_size,
                              hipStream_t stream) {
    (void)in_sizes; (void)n_in;
    const float* x  = (const float*)d_in[0];
    const float* fr = (const float*)d_in[1];
    const float* fi = (const float*)d_in[2];

    const int cplx = (out_size >= BATCH * NPTS * 2) ? 1 : 0;
    const size_t g_bytes = (size_t)BATCH * GSTRIDE * sizeof(__half2);  // 525 KB

    if (ws_size >= g_bytes) {
        __half2* g16 = (__half2*)d_ws;
        nfft_fft_kernel<<<BATCH * 16, 256, 0, stream>>>(fr, fi, g16);
        nfft_interp_kernel<<<BATCH * 32, 1024, 0, stream>>>(
            x, g16, (float*)d_out, cplx);
    } else {
        nfft_fused_kernel<<<BATCH * 32, 1024, 0, stream>>>(
            x, fr, fi, (float*)d_out, cplx);
    }
}